// Round 6
// baseline (205.793 us; speedup 1.0000x reference)
//
#include <hip/hip_runtime.h>
#include <hip/hip_bf16.h>

// Problem constants (fixed by the reference)
#define CS     128
#define EDIM   256
#define NBATCH 2
#define TLEN   8192
#define NCHUNK 64
#define LEXT   1024
#define KSEL   7

typedef __attribute__((ext_vector_type(8))) short   short8;   // 8 bf16 = 4 VGPR (MFMA A/B frag)
typedef __attribute__((ext_vector_type(4))) float   floatx4;  // MFMA C/D frag

__device__ inline short bf16_of(float f) {
    __hip_bfloat16 h = __float2bfloat16(f);
    return *(short*)&h;
}
__device__ inline float f_of_bf16(short s) {
    __hip_bfloat16 h = *(__hip_bfloat16*)&s;
    return __bfloat162float(h);
}

// async global->LDS, 16B per lane; LDS dest = wave-uniform base + lane*16
__device__ inline void gl_lds16(const void* g, void* l) {
    __builtin_amdgcn_global_load_lds(
        (const __attribute__((address_space(1))) unsigned int*)g,
        (__attribute__((address_space(3))) unsigned int*)l, 16, 0, 0);
}

// raw barrier (no compiler vmcnt(0) drain) — counted vmcnt crosses it
#define RAW_BAR() asm volatile("s_barrier" ::: "memory")

// ---------------------------------------------------------------------------
// Fused prep: one x read -> cn_hi/cn_lo + xt_hi ; 8 tail blocks convert dp.
// (r12/round-1 version, row-major cn layout — unchanged, proven)
// ---------------------------------------------------------------------------
__global__ __launch_bounds__(256) void prep_kernel(const float* __restrict__ x,
                                                   const float* __restrict__ dp,
                                                   short* __restrict__ cn_hi,
                                                   short* __restrict__ cn_lo,
                                                   short* __restrict__ xt_hi,
                                                   short* __restrict__ dp_hi) {
    const int bx = blockIdx.x;
    if (bx >= 256) {            // dp conversion: 8 blocks x 256 thr x 16 float4
        int t = (bx - 256) * 256 + threadIdx.x;
#pragma unroll
        for (int u = 0; u < 16; ++u) {
            int idx = (t * 16 + u) * 4;
            float4 v = *(const float4*)(dp + idx);
            *(short4*)(dp_hi + idx) =
                make_short4(bf16_of(v.x), bf16_of(v.y), bf16_of(v.z), bf16_of(v.w));
        }
        return;
    }

    __shared__ float tile[64 * 257];   // [t-row][e], pitch 257
    const int b = bx >> 7, t0 = (bx & 127) * 64;
    const int tid = threadIdx.x;
    const int r = tid >> 2, q = tid & 3;   // row r (0..63), quarter q (64 elems)

    const float* src = x + ((size_t)(b * TLEN + t0 + r)) * EDIM + q * 64;
    float* trow = &tile[r * 257 + q * 64];
    float s = 0.f;
#pragma unroll
    for (int u = 0; u < 16; ++u) {
        float4 v = *(const float4*)(src + u * 4);
        s += v.x * v.x + v.y * v.y + v.z * v.z + v.w * v.w;
        trow[u * 4 + 0] = v.x; trow[u * 4 + 1] = v.y;
        trow[u * 4 + 2] = v.z; trow[u * 4 + 3] = v.w;
    }
    s += __shfl_xor(s, 1);
    s += __shfl_xor(s, 2);
    const float rn = 1.0f / (sqrtf(s) + 1e-6f);

    short* ch = cn_hi + ((size_t)(b * TLEN + t0 + r)) * EDIM + q * 64;
    short* cl = cn_lo + ((size_t)(b * TLEN + t0 + r)) * EDIM + q * 64;
#pragma unroll
    for (int u = 0; u < 16; ++u) {
        short hs[4], ls[4];
#pragma unroll
        for (int k2 = 0; k2 < 4; ++k2) {
            float c = trow[u * 4 + k2] * rn;
            hs[k2] = bf16_of(c);
            ls[k2] = bf16_of(c - f_of_bf16(hs[k2]));
        }
        *(short4*)(ch + u * 4) = make_short4(hs[0], hs[1], hs[2], hs[3]);
        *(short4*)(cl + u * 4) = make_short4(ls[0], ls[1], ls[2], ls[3]);
    }
    __syncthreads();

    const int g16 = tid >> 4, tq = tid & 15;
#pragma unroll
    for (int it = 0; it < 16; ++it) {
        int e = g16 + it * 16;
        short hs2[4];
#pragma unroll
        for (int g = 0; g < 4; ++g)
            hs2[g] = bf16_of(tile[(tq * 4 + g) * 257 + e]);
        *(short4*)(xt_hi + ((size_t)(b * EDIM + e)) * TLEN + t0 + tq * 4)
            = make_short4(hs2[0], hs2[1], hs2[2], hs2[3]);
    }
}

// ---------------------------------------------------------------------------
// Stage B v6: 2x2 superchunk pair-tiling. Block = superpair (I,J), J<=I,
// computes the 4 chunk-pairs {2I,2I+1} x {2J,2J+1}: stages 4 chunks
// (512 KB) for 4 pairs = 128 KB/pair, HALF the per-pair L3->LDS traffic of
// the 1-pair kernel (measured occupancy-invariant MfmaUtil ~40% implicated
// the staging path, not latency hiding).
// Retained verbatim from the proven r1 kernel: row-major cn layout, csw/q8
// XOR swizzle pair, per-wave 8x gl_lds staging (vmcnt(8) counted across raw
// barriers), 16x16x32 split-bf16 MFMA (ah*bh + ah*bl + al*bh), setprio.
// 512 thr / 8 waves: wave w stages tile (chunk w>>1, hi/lo w&1); computes
// pair p = w>>1, row-half h = w&1 (64x128 output, acc[4][8], ct-outer).
// LDS 2 x 64 KB = 128 KB -> 1 block/CU, 2 waves/SIMD (r1's occupancy).
// ---------------------------------------------------------------------------
__global__ __launch_bounds__(512, 2) void scores_mfma(const short* __restrict__ cn_hi,
                                                      const short* __restrict__ cn_lo,
                                                      float* __restrict__ scores) {
    __shared__ short tiles[2][4][2][4096];      // [buf][chunk][hi/lo][8KB] = 128 KB
    double* red2   = (double*)&tiles[0][0][0][0];            // 8 doubles (epilogue)
    float*  redbuf = (float*)((char*)&tiles[0][0][0][0] + 64); // 512 floats (epilogue)

    const int p = blockIdx.x, b = blockIdx.y;
    // decode superpair: p = I*(I+1)/2 + J, J <= I, I in 0..31
    int I = (int)((sqrtf(8.0f * (float)p + 1.0f) - 1.0f) * 0.5f);
    while (I * (I + 1) / 2 > p) --I;
    while ((I + 1) * (I + 2) / 2 <= p) ++I;
    const int J = p - I * (I + 1) / 2;

    const int tid  = threadIdx.x;
    const int w    = tid >> 6, lane = tid & 63;
    const int pr   = w >> 1, h = w & 1;            // pair index, row-half
    const int quad = lane >> 4, l15 = lane & 15;

    // staging role: chunk c = w>>1 (i0,i1,j0,j1), precision hl = w&1
    const int c_stage = w >> 1, hl = w & 1;
    const int chunk_c = (c_stage < 2) ? (2 * I + c_stage) : (2 * J + (c_stage - 2));
    const short* sarr  = hl ? cn_lo : cn_hi;
    const size_t sbase = ((size_t)b * TLEN + (size_t)chunk_c * CS) * EDIM;
    const int rr  = lane >> 2;
    const int c16 = (lane & 3) * 8;
    const int csw = c16 ^ (((rr >> 1) & 3) * 8);       // staging swizzle
    const int q8  = (quad ^ ((l15 >> 1) & 3)) * 8;     // frag-read swizzle

    // wave w stages its full 8 KB tile (chunk c_stage, precision hl): 8x1KB
    auto stage = [&](int ks, int bf) {
        const short* gsrc = sarr + sbase + ks * 32 + csw;
        short* ldst = &tiles[bf][c_stage][hl][0];
#pragma unroll
        for (int t = 0; t < 8; ++t)
            gl_lds16(gsrc + (size_t)(16 * t + rr) * EDIM, ldst + t * 512);
    };

    // compute-side tile indices for this wave's pair
    const int ci = pr >> 1;          // 0/1 -> chunk 2I / 2I+1
    const int cj = 2 + (pr & 1);     // 2/3 -> chunk 2J / 2J+1

    floatx4 acc[4][8];
#pragma unroll
    for (int rt = 0; rt < 4; ++rt)
#pragma unroll
        for (int ct = 0; ct < 8; ++ct) acc[rt][ct] = (floatx4){0.f, 0.f, 0.f, 0.f};

    stage(0, 0);
    int buf = 0;
    for (int ks = 0; ks < 8; ++ks) {
        if (ks < 7) {
            stage(ks + 1, buf ^ 1);                       // 8 loads in flight
            asm volatile("s_waitcnt vmcnt(8)" ::: "memory");  // old 8 landed
        } else {
            asm volatile("s_waitcnt vmcnt(0)" ::: "memory");
        }
        RAW_BAR();   // all waves' current-buf tiles have landed

        // preload A fragments (rows h*64 + rt*16 + l15 of chunk ci)
        short8 ah[4], al[4];
#pragma unroll
        for (int rt = 0; rt < 4; ++rt) {
            int r = h * 64 + rt * 16 + l15;
            ah[rt] = *(const short8*)&tiles[buf][ci][0][r * 32 + q8];
            al[rt] = *(const short8*)&tiles[buf][ci][1][r * 32 + q8];
        }
        __builtin_amdgcn_s_setprio(1);
#pragma unroll
        for (int ct = 0; ct < 8; ++ct) {
            int r = ct * 16 + l15;
            short8 bh = *(const short8*)&tiles[buf][cj][0][r * 32 + q8];
            short8 bl = *(const short8*)&tiles[buf][cj][1][r * 32 + q8];
#pragma unroll
            for (int rt = 0; rt < 4; ++rt) {
                acc[rt][ct] = __builtin_amdgcn_mfma_f32_16x16x32_bf16(ah[rt], bh, acc[rt][ct], 0, 0, 0);
                acc[rt][ct] = __builtin_amdgcn_mfma_f32_16x16x32_bf16(ah[rt], bl, acc[rt][ct], 0, 0, 0);
                acc[rt][ct] = __builtin_amdgcn_mfma_f32_16x16x32_bf16(al[rt], bh, acc[rt][ct], 0, 0, 0);
            }
        }
        __builtin_amdgcn_s_setprio(0);
        RAW_BAR();   // all waves done reading buf before next stage overwrites
        buf ^= 1;
    }

    __syncthreads();   // safe to alias tiles[0] for reduction buffers

    // per-row max over the pair's 128 cols (8 ct in-reg, then l15 shuffle)
#pragma unroll
    for (int rt = 0; rt < 4; ++rt) {
        float m[4];
#pragma unroll
        for (int reg = 0; reg < 4; ++reg) {
            float mm = acc[rt][0][reg];
#pragma unroll
            for (int ct = 1; ct < 8; ++ct) mm = fmaxf(mm, acc[rt][ct][reg]);
            m[reg] = mm;
        }
#pragma unroll
        for (int off = 1; off < 16; off <<= 1)
#pragma unroll
            for (int reg = 0; reg < 4; ++reg) m[reg] = fmaxf(m[reg], __shfl_xor(m[reg], off));
        if (l15 == 0) {
#pragma unroll
            for (int reg = 0; reg < 4; ++reg)
                redbuf[pr * 128 + h * 64 + rt * 16 + quad * 4 + reg] = m[reg];
        }
    }
    __syncthreads();

    // sum of row-maxes per pair (double, as proven): wave wid covers 64 rows
    {
        const int tp = tid >> 7, row = tid & 127;
        double part = (double)redbuf[tp * 128 + row];
#pragma unroll
        for (int off = 1; off < 64; off <<= 1) part += __shfl_xor(part, off);
        if (lane == 0) red2[w] = part;   // wave w = 2*tp + (row>>6)
    }
    __syncthreads();
    if (tid < 4) {
        const int a = tid >> 1, bs = tid & 1;
        const int i_g = 2 * I + a, j_g = 2 * J + bs;
        if (j_g < i_g) {
            double sum = red2[2 * tid] + red2[2 * tid + 1];
            scores[(b * NCHUNK + i_g) * NCHUNK + j_g] = (float)sum;
        }
    }
}

// ---------------------------------------------------------------------------
// Stage D v7 (measured best): out = dp @ ext + chunk, K=64 steps (2 k32
// sub-slices each), 3 LDS buffers, prefetch depth 2, ONE raw barrier per
// step, counted per-wave vmcnt. Unchanged.
// ---------------------------------------------------------------------------
__global__ __launch_bounds__(256) void out_mfma(const float* __restrict__ x,
                                                const short* __restrict__ dph,
                                                const short* __restrict__ xth,
                                                const float* __restrict__ scores,
                                                float* __restrict__ out) {
    __shared__ short As[3][2][128 * 32];   // [buf][sub][c][k]  48 KB
    __shared__ short Bs[3][2][64 * 32];    // [buf][sub][e][k]  24 KB
    __shared__ int   slist[8], sslot[8], snum;
    __shared__ float swei[8];

    const int eq = blockIdx.x, n = blockIdx.y, b = blockIdx.z;
    const int e0 = eq * 64;
    const int tid  = threadIdx.x;
    const int w    = tid >> 6, lane = tid & 63;
    const int wr   = w >> 1, wc = w & 1;
    const int quad = lane >> 4, l15 = lane & 15;
    const int rr   = lane >> 2;
    const int c16  = (lane & 3) * 8;
    const int csw  = c16 ^ (((rr >> 1) & 3) * 8);
    const int q8   = (quad ^ ((l15 >> 1) & 3)) * 8;

    // ---- inlined top-7 (wave 0): candidates j in [0, n) ----
    if (w == 0) {
        const float* srow = scores + (b * NCHUNK + n) * NCHUNK;
        const int nsel = n < KSEL ? n : KSEL;
        float v = (lane < n) ? srow[lane] : -3.0e38f;
        float vals[KSEL];
        int   idxs[KSEL];
        for (int s2 = 0; s2 < nsel; ++s2) {
            float bv = v; int bi = lane;
#pragma unroll
            for (int off = 1; off < 64; off <<= 1) {
                float ov = __shfl_xor(bv, off);
                int   oi = __shfl_xor(bi, off);
                if (ov > bv || (ov == bv && oi < bi)) { bv = ov; bi = oi; }
            }
            vals[s2] = bv; idxs[s2] = bi;
            if (lane == bi) v = -3.0e38f;
        }
        if (lane == 0) {
            float vmin = (nsel > 0) ? vals[nsel - 1] : 0.0f;
            float inv  = 1.0f / (vmin + 1e-6f);
            int shift  = KSEL - nsel;
            int c = 0;
            for (int s2 = 0; s2 < 8; ++s2) {
                int jj; float ww;
                if (s2 < KSEL) {
                    int tt = s2 - shift;
                    if (tt >= 0) { jj = idxs[tt]; ww = vals[tt] * inv; }
                    else         { jj = -1;       ww = 0.0f; }
                } else { jj = n; ww = 1.0f; }
                if (jj >= 0) { slist[c] = jj; sslot[c] = s2; swei[c] = ww; ++c; }
            }
            snum = c;
        }
    }
    __syncthreads();
    const int NT = snum * 2;   // K=64 steps (2 k32 sub-slices per step)

    // stage step st into buffer b3: waves 0-1 stage As (8 loads), 2-3 Bs (4)
    auto stage = [&](int st, int b3) {
        int sv = st >> 1, kh = st & 1;
        if (w < 2) {
#pragma unroll
            for (int sub = 0; sub < 2; ++sub) {
                const short* gsrc = dph + (size_t)(sslot[sv] * 128 + (kh * 2 + sub) * 32) + csw;
#pragma unroll
                for (int t = 0; t < 4; ++t)
                    gl_lds16(gsrc + (size_t)(w * 64 + t * 16 + rr) * LEXT,
                             &As[b3][sub][(w * 64 + t * 16) * 32]);
            }
        } else {
#pragma unroll
            for (int sub = 0; sub < 2; ++sub) {
                const short* gsrc = xth + ((size_t)(b * EDIM + e0)) * TLEN
                                    + (size_t)(slist[sv] * CS + (kh * 2 + sub) * 32) + csw;
#pragma unroll
                for (int t = 0; t < 2; ++t)
                    gl_lds16(gsrc + (size_t)((w - 2) * 32 + t * 16 + rr) * TLEN,
                             &Bs[b3][sub][((w - 2) * 32 + t * 16) * 32]);
            }
        }
    };

    floatx4 accT[4][2], accP[4][2];
#pragma unroll
    for (int rt = 0; rt < 4; ++rt)
#pragma unroll
        for (int ct = 0; ct < 2; ++ct) accT[rt][ct] = (floatx4){0.f, 0.f, 0.f, 0.f};

    stage(0, 0);
    if (NT > 1) stage(1, 1);
    // ensure stage 0 landed (allow stage 1's loads to remain in flight)
    if (w < 2) asm volatile("s_waitcnt vmcnt(8)" ::: "memory");
    else       asm volatile("s_waitcnt vmcnt(4)" ::: "memory");

    int cur = 0;
    for (int st = 0; st < NT; ++st) {
        RAW_BAR();   // all waves: buf 'cur' landed, and compute(st-1) finished

        if ((st & 1) == 0) {
#pragma unroll
            for (int rt = 0; rt < 4; ++rt)
#pragma unroll
                for (int ct = 0; ct < 2; ++ct) accP[rt][ct] = (floatx4){0.f, 0.f, 0.f, 0.f};
        }

#pragma unroll
        for (int sub = 0; sub < 2; ++sub) {
            short8 bh[2];
#pragma unroll
            for (int ct = 0; ct < 2; ++ct) {
                int e = wc * 32 + ct * 16 + l15;
                bh[ct] = *(const short8*)&Bs[cur][sub][e * 32 + q8];
            }
            __builtin_amdgcn_s_setprio(1);
#pragma unroll
            for (int rt = 0; rt < 4; ++rt) {
                int r = wr * 64 + rt * 16 + l15;
                short8 ah = *(const short8*)&As[cur][sub][r * 32 + q8];
#pragma unroll
                for (int ct = 0; ct < 2; ++ct)
                    accP[rt][ct] = __builtin_amdgcn_mfma_f32_16x16x32_bf16(ah, bh[ct], accP[rt][ct], 0, 0, 0);
            }
            __builtin_amdgcn_s_setprio(0);
        }

        if ((st & 1) == 1) {
            float wcur = swei[st >> 1];
#pragma unroll
            for (int rt = 0; rt < 4; ++rt)
#pragma unroll
                for (int ct = 0; ct < 2; ++ct)
#pragma unroll
                    for (int reg = 0; reg < 4; ++reg)
                        accT[rt][ct][reg] += wcur * accP[rt][ct][reg];
        }

        if (st + 2 < NT) {
            int tgt = cur ? cur - 1 : 2;        // (cur+2)%3
            stage(st + 2, tgt);
            if (w < 2) asm volatile("s_waitcnt vmcnt(8)" ::: "memory");
            else       asm volatile("s_waitcnt vmcnt(4)" ::: "memory");
        } else if (st + 1 < NT) {
            asm volatile("s_waitcnt vmcnt(0)" ::: "memory");
        }
        cur = (cur == 2) ? 0 : cur + 1;
    }

#pragma unroll
    for (int rt = 0; rt < 4; ++rt)
#pragma unroll
        for (int ct = 0; ct < 2; ++ct) {
#pragma unroll
            for (int reg = 0; reg < 4; ++reg) {
                int row = wr * 64 + rt * 16 + quad * 4 + reg;
                int col = wc * 32 + ct * 16 + l15;
                size_t o = ((size_t)(b * TLEN + n * CS + row)) * EDIM + e0 + col;
                out[o] = accT[rt][ct][reg] + x[o];
            }
        }
}

// ---------------------------------------------------------------------------
extern "C" void kernel_launch(void* const* d_in, const int* in_sizes, int n_in,
                              void* d_out, int out_size, void* d_ws, size_t ws_size,
                              hipStream_t stream) {
    const float* x  = (const float*)d_in[0];   // [2, 8192, 256] fp32
    const float* dp = (const float*)d_in[1];   // [128, 1024] fp32
    float* out = (float*)d_out;

    char* ws = (char*)d_ws;
    short* cn_hi  = (short*)(ws);                       // 8 MB
    short* cn_lo  = (short*)(ws + (8u << 20));          // 8 MB
    short* xt_hi  = (short*)(ws + (16u << 20));         // 8 MB
    short* dp_hi  = (short*)(ws + (24u << 20));         // 256 KB
    float* scores = (float*)(ws + (25u << 20));         // 32 KB

    prep_kernel <<<dim3(264), 256, 0, stream>>>(x, dp, cn_hi, cn_lo, xt_hi, dp_hi);
    scores_mfma <<<dim3(32 * 33 / 2, NBATCH), 512, 0, stream>>>(cn_hi, cn_lo, scores);
    out_mfma    <<<dim3(4, NCHUNK, NBATCH), 256, 0, stream>>>(x, dp_hi, xt_hi, scores, out);
}

// Round 7
// 200.034 us; speedup vs baseline: 1.0288x; 1.0288x over previous
//
#include <hip/hip_runtime.h>
#include <hip/hip_bf16.h>

// Problem constants (fixed by the reference)
#define CS     128
#define EDIM   256
#define NBATCH 2
#define TLEN   8192
#define NCHUNK 64
#define LEXT   1024
#define KSEL   7

typedef __attribute__((ext_vector_type(8))) short   short8;   // 8 bf16 = 4 VGPR (MFMA A/B frag)
typedef __attribute__((ext_vector_type(4))) float   floatx4;  // MFMA C/D frag

__device__ inline short bf16_of(float f) {
    __hip_bfloat16 h = __float2bfloat16(f);
    return *(short*)&h;
}
__device__ inline float f_of_bf16(short s) {
    __hip_bfloat16 h = *(__hip_bfloat16*)&s;
    return __bfloat162float(h);
}

// async global->LDS, 16B per lane; LDS dest = wave-uniform base + lane*16
__device__ inline void gl_lds16(const void* g, void* l) {
    __builtin_amdgcn_global_load_lds(
        (const __attribute__((address_space(1))) unsigned int*)g,
        (__attribute__((address_space(3))) unsigned int*)l, 16, 0, 0);
}

// raw barrier (no compiler vmcnt(0) drain) — counted vmcnt crosses it
#define RAW_BAR() asm volatile("s_barrier" ::: "memory")

// ---------------------------------------------------------------------------
// Fused prep: one x read -> cn_hi/cn_lo (row-major, as scores r1 expects)
// + xkt (k-sliced chunk-local x^T: [b][chunk][kk 4][e 256][k 32]) ;
// 8 tail blocks convert dp into dpk ([slot 8][kk 4][c 128][k 32]).
// The k-sliced layouts make every A/B tile out_mfma stages a CONTIGUOUS
// block (each gl_lds = 1 KB contiguous), replacing the 16-way 64B scatter
// of the [e][T] / [c][L] layouts.
// ---------------------------------------------------------------------------
__global__ __launch_bounds__(256) void prep_kernel(const float* __restrict__ x,
                                                   const float* __restrict__ dp,
                                                   short* __restrict__ cn_hi,
                                                   short* __restrict__ cn_lo,
                                                   short* __restrict__ xkt,
                                                   short* __restrict__ dpk) {
    const int bx = blockIdx.x;
    if (bx >= 256) {            // dp conversion: 8 blocks x 256 thr x 16 float4
        int t = (bx - 256) * 256 + threadIdx.x;
#pragma unroll
        for (int u = 0; u < 16; ++u) {
            int idx = (t * 16 + u) * 4;
            float4 v = *(const float4*)(dp + idx);
            int c = idx >> 10, l = idx & 1023;
            int s = l >> 7, kk = (l >> 5) & 3, kq = l & 31;   // 4-elem group stays in one kk
            int na = ((s * 4 + kk) * 128 + c) * 32 + kq;
            *(short4*)(dpk + na) =
                make_short4(bf16_of(v.x), bf16_of(v.y), bf16_of(v.z), bf16_of(v.w));
        }
        return;
    }

    __shared__ float tile[64 * 257];   // [t-row][e], pitch 257
    const int b = bx >> 7, t0 = (bx & 127) * 64;
    const int tid = threadIdx.x;
    const int r = tid >> 2, q = tid & 3;   // row r (0..63), quarter q (64 elems)

    const float* src = x + ((size_t)(b * TLEN + t0 + r)) * EDIM + q * 64;
    float* trow = &tile[r * 257 + q * 64];
    float s = 0.f;
#pragma unroll
    for (int u = 0; u < 16; ++u) {
        float4 v = *(const float4*)(src + u * 4);
        s += v.x * v.x + v.y * v.y + v.z * v.z + v.w * v.w;
        trow[u * 4 + 0] = v.x; trow[u * 4 + 1] = v.y;
        trow[u * 4 + 2] = v.z; trow[u * 4 + 3] = v.w;
    }
    s += __shfl_xor(s, 1);
    s += __shfl_xor(s, 2);
    const float rn = 1.0f / (sqrtf(s) + 1e-6f);

    short* ch = cn_hi + ((size_t)(b * TLEN + t0 + r)) * EDIM + q * 64;
    short* cl = cn_lo + ((size_t)(b * TLEN + t0 + r)) * EDIM + q * 64;
#pragma unroll
    for (int u = 0; u < 16; ++u) {
        short hs[4], ls[4];
#pragma unroll
        for (int k2 = 0; k2 < 4; ++k2) {
            float c = trow[u * 4 + k2] * rn;
            hs[k2] = bf16_of(c);
            ls[k2] = bf16_of(c - f_of_bf16(hs[k2]));
        }
        *(short4*)(ch + u * 4) = make_short4(hs[0], hs[1], hs[2], hs[3]);
        *(short4*)(cl + u * 4) = make_short4(ls[0], ls[1], ls[2], ls[3]);
    }
    __syncthreads();

    // xkt write: chunk-local transposed k-sliced layout.
    // thread (g16, tq) writes e = g16 + it*16, k_local = (t0&64) + tq*4 + g.
    const int g16 = tid >> 4, tq = tid & 15;
    const int chunk = t0 >> 7;
    const int kbase = (t0 & 64) + tq * 4;       // same kk for g=0..3
    const int kk = kbase >> 5, kq = kbase & 31;
    short* xbase = xkt + ((size_t)(((b * 64 + chunk) * 4 + kk) * 256)) * 32 + kq;
#pragma unroll
    for (int it = 0; it < 16; ++it) {
        int e = g16 + it * 16;
        short hs2[4];
#pragma unroll
        for (int g = 0; g < 4; ++g)
            hs2[g] = bf16_of(tile[(tq * 4 + g) * 257 + e]);
        *(short4*)(xbase + (size_t)e * 32) = make_short4(hs2[0], hs2[1], hs2[2], hs2[3]);
    }
}

// ---------------------------------------------------------------------------
// Stage B (round-1 proven version, verbatim): split-bf16 16x16x32 MFMA cosine
// scores, XOR bank swizzle, double-buffered LDS (64 KB), counted vmcnt(8)
// across raw barriers, setprio. Measured twice: 110.8-111.6 us, MfmaUtil
// ~41%, SQ_LDS_BANK_CONFLICT 0. Occupancy/traffic/shape experiments (r2-r6)
// all failed to beat it — structural plateau, do not touch.
// ---------------------------------------------------------------------------
__global__ __launch_bounds__(256) void scores_mfma(const short* __restrict__ cn_hi,
                                                   const short* __restrict__ cn_lo,
                                                   float* __restrict__ scores) {
    __shared__ short tiles[2][4][4096];         // [buf][tile][..] 64 KB exactly
    double* red2   = (double*)&tiles[0][0][0];  // alias (epilogue only)
    float*  redbuf = (float*)&tiles[0][0][8];   // alias, bytes [16, 1040)

    const int p = blockIdx.x, b = blockIdx.y;
    int i = (int)((1.0f + sqrtf(1.0f + 8.0f * (float)p)) * 0.5f);
    while (i * (i - 1) / 2 > p) --i;
    while (i * (i + 1) / 2 <= p) ++i;
    const int j = p - i * (i - 1) / 2;

    const int tid  = threadIdx.x;
    const int w    = tid >> 6, lane = tid & 63;
    const int wr   = w >> 1, wc = w & 1;
    const int quad = lane >> 4, l15 = lane & 15;

    const short* sarr  = (w & 1) ? cn_lo : cn_hi;
    const size_t sbase = ((size_t)b * TLEN + ((w >> 1) ? j : i) * CS) * EDIM;
    const int rr  = lane >> 2;
    const int c16 = (lane & 3) * 8;
    const int csw = c16 ^ (((rr >> 1) & 3) * 8);       // staging swizzle
    const int q8  = (quad ^ ((l15 >> 1) & 3)) * 8;     // frag-read swizzle

    // each wave stages its own tile (w: A_hi / A_lo / B_hi / B_lo), 8x1KB
    auto stage = [&](int ks, int bf) {
        const short* gsrc = sarr + sbase + ks * 32 + csw;
        short* ldst = &tiles[bf][w][0];
#pragma unroll
        for (int t = 0; t < 8; ++t)
            gl_lds16(gsrc + (size_t)(16 * t + rr) * EDIM, ldst + t * 512);
    };

    floatx4 acc[4][4];
#pragma unroll
    for (int rt = 0; rt < 4; ++rt)
#pragma unroll
        for (int ct = 0; ct < 4; ++ct) acc[rt][ct] = (floatx4){0.f, 0.f, 0.f, 0.f};

    stage(0, 0);
    int buf = 0;
    for (int ks = 0; ks < 8; ++ks) {
        if (ks < 7) {
            stage(ks + 1, buf ^ 1);                       // 8 loads in flight
            asm volatile("s_waitcnt vmcnt(8)" ::: "memory");  // old 8 landed
        } else {
            asm volatile("s_waitcnt vmcnt(0)" ::: "memory");
        }
        RAW_BAR();   // all waves' current-buf loads have landed

        short8 bh[4], bl[4];
#pragma unroll
        for (int ct = 0; ct < 4; ++ct) {
            int r = wc * 64 + ct * 16 + l15;
            bh[ct] = *(const short8*)&tiles[buf][2][r * 32 + q8];
            bl[ct] = *(const short8*)&tiles[buf][3][r * 32 + q8];
        }
        __builtin_amdgcn_s_setprio(1);
#pragma unroll
        for (int rt = 0; rt < 4; ++rt) {
            int r = wr * 64 + rt * 16 + l15;
            short8 ah = *(const short8*)&tiles[buf][0][r * 32 + q8];
            short8 al = *(const short8*)&tiles[buf][1][r * 32 + q8];
#pragma unroll
            for (int ct = 0; ct < 4; ++ct) {
                acc[rt][ct] = __builtin_amdgcn_mfma_f32_16x16x32_bf16(ah, bh[ct], acc[rt][ct], 0, 0, 0);
                acc[rt][ct] = __builtin_amdgcn_mfma_f32_16x16x32_bf16(ah, bl[ct], acc[rt][ct], 0, 0, 0);
                acc[rt][ct] = __builtin_amdgcn_mfma_f32_16x16x32_bf16(al, bh[ct], acc[rt][ct], 0, 0, 0);
            }
        }
        __builtin_amdgcn_s_setprio(0);
        RAW_BAR();   // all waves done reading buf before next stage overwrites
        buf ^= 1;
    }

#pragma unroll
    for (int rt = 0; rt < 4; ++rt) {
        float m[4];
#pragma unroll
        for (int reg = 0; reg < 4; ++reg) {
            float mm = acc[rt][0][reg];
#pragma unroll
            for (int ct = 1; ct < 4; ++ct) mm = fmaxf(mm, acc[rt][ct][reg]);
            m[reg] = mm;
        }
#pragma unroll
        for (int off = 1; off < 16; off <<= 1)
#pragma unroll
            for (int reg = 0; reg < 4; ++reg) m[reg] = fmaxf(m[reg], __shfl_xor(m[reg], off));
        if (l15 == 0) {
#pragma unroll
            for (int reg = 0; reg < 4; ++reg)
                redbuf[wc * 128 + wr * 64 + rt * 16 + quad * 4 + reg] = m[reg];
        }
    }
    __syncthreads();

    double part = 0.0;
    if (tid < 128) part = (double)fmaxf(redbuf[tid], redbuf[128 + tid]);
#pragma unroll
    for (int off = 1; off < 64; off <<= 1) part += __shfl_xor(part, off);
    if (lane == 0 && w < 2) red2[w] = part;
    __syncthreads();
    if (tid == 0) scores[(b * NCHUNK + i) * NCHUNK + j] = (float)(red2[0] + red2[1]);
}

// ---------------------------------------------------------------------------
// Stage D v9: v7 schedule (K=64 steps, 3 LDS buffers, prefetch depth 2, ONE
// raw barrier per step, counted per-wave vmcnt) with staging retargeted to
// the contiguous k-sliced layouts dpk/xkt. Row stride TLEN/LEXT -> 32, so
// each gl_lds covers 1 KB contiguous (was 16 scattered 64B segments).
// LDS image, csw/q8 swizzle pair, and all MFMA math bit-identical to v7.
// ---------------------------------------------------------------------------
__global__ __launch_bounds__(256) void out_mfma(const float* __restrict__ x,
                                                const short* __restrict__ dpk,
                                                const short* __restrict__ xkt,
                                                const float* __restrict__ scores,
                                                float* __restrict__ out) {
    __shared__ short As[3][2][128 * 32];   // [buf][sub][c][k]  48 KB
    __shared__ short Bs[3][2][64 * 32];    // [buf][sub][e][k]  24 KB
    __shared__ int   slist[8], sslot[8], snum;
    __shared__ float swei[8];

    const int eq = blockIdx.x, n = blockIdx.y, b = blockIdx.z;
    const int e0 = eq * 64;
    const int tid  = threadIdx.x;
    const int w    = tid >> 6, lane = tid & 63;
    const int wr   = w >> 1, wc = w & 1;
    const int quad = lane >> 4, l15 = lane & 15;
    const int rr   = lane >> 2;
    const int c16  = (lane & 3) * 8;
    const int csw  = c16 ^ (((rr >> 1) & 3) * 8);
    const int q8   = (quad ^ ((l15 >> 1) & 3)) * 8;

    // ---- inlined top-7 (wave 0): candidates j in [0, n) ----
    if (w == 0) {
        const float* srow = scores + (b * NCHUNK + n) * NCHUNK;
        const int nsel = n < KSEL ? n : KSEL;
        float v = (lane < n) ? srow[lane] : -3.0e38f;
        float vals[KSEL];
        int   idxs[KSEL];
        for (int s2 = 0; s2 < nsel; ++s2) {
            float bv = v; int bi = lane;
#pragma unroll
            for (int off = 1; off < 64; off <<= 1) {
                float ov = __shfl_xor(bv, off);
                int   oi = __shfl_xor(bi, off);
                if (ov > bv || (ov == bv && oi < bi)) { bv = ov; bi = oi; }
            }
            vals[s2] = bv; idxs[s2] = bi;
            if (lane == bi) v = -3.0e38f;
        }
        if (lane == 0) {
            float vmin = (nsel > 0) ? vals[nsel - 1] : 0.0f;
            float inv  = 1.0f / (vmin + 1e-6f);
            int shift  = KSEL - nsel;
            int c = 0;
            for (int s2 = 0; s2 < 8; ++s2) {
                int jj; float ww;
                if (s2 < KSEL) {
                    int tt = s2 - shift;
                    if (tt >= 0) { jj = idxs[tt]; ww = vals[tt] * inv; }
                    else         { jj = -1;       ww = 0.0f; }
                } else { jj = n; ww = 1.0f; }
                if (jj >= 0) { slist[c] = jj; sslot[c] = s2; swei[c] = ww; ++c; }
            }
            snum = c;
        }
    }
    __syncthreads();
    const int NT = snum * 2;   // K=64 steps (2 k32 sub-slices per step)

    // stage step st into buffer b3: waves 0-1 stage As (8 loads), 2-3 Bs (4).
    // dpk tile (slot, kk): contiguous 8 KB at ((slot*4+kk)*128)*32.
    // xkt tile (chunk, kk): contiguous at (((b*64+chunk)*4+kk)*256 + e)*32.
    auto stage = [&](int st, int b3) {
        int sv = st >> 1, kh = st & 1;
        if (w < 2) {
#pragma unroll
            for (int sub = 0; sub < 2; ++sub) {
                const short* gsrc = dpk
                    + (size_t)((sslot[sv] * 4 + kh * 2 + sub) * 128) * 32 + csw;
#pragma unroll
                for (int t = 0; t < 4; ++t)
                    gl_lds16(gsrc + (size_t)(w * 64 + t * 16 + rr) * 32,
                             &As[b3][sub][(w * 64 + t * 16) * 32]);
            }
        } else {
#pragma unroll
            for (int sub = 0; sub < 2; ++sub) {
                const short* gsrc = xkt
                    + (size_t)((((b * 64 + slist[sv]) * 4 + kh * 2 + sub) * 256) + e0) * 32 + csw;
#pragma unroll
                for (int t = 0; t < 2; ++t)
                    gl_lds16(gsrc + (size_t)((w - 2) * 32 + t * 16 + rr) * 32,
                             &Bs[b3][sub][((w - 2) * 32 + t * 16) * 32]);
            }
        }
    };

    floatx4 accT[4][2], accP[4][2];
#pragma unroll
    for (int rt = 0; rt < 4; ++rt)
#pragma unroll
        for (int ct = 0; ct < 2; ++ct) accT[rt][ct] = (floatx4){0.f, 0.f, 0.f, 0.f};

    stage(0, 0);
    if (NT > 1) stage(1, 1);
    // ensure stage 0 landed (allow stage 1's loads to remain in flight)
    if (w < 2) asm volatile("s_waitcnt vmcnt(8)" ::: "memory");
    else       asm volatile("s_waitcnt vmcnt(4)" ::: "memory");

    int cur = 0;
    for (int st = 0; st < NT; ++st) {
        RAW_BAR();   // all waves: buf 'cur' landed, and compute(st-1) finished

        if ((st & 1) == 0) {
#pragma unroll
            for (int rt = 0; rt < 4; ++rt)
#pragma unroll
                for (int ct = 0; ct < 2; ++ct) accP[rt][ct] = (floatx4){0.f, 0.f, 0.f, 0.f};
        }

#pragma unroll
        for (int sub = 0; sub < 2; ++sub) {
            short8 bh[2];
#pragma unroll
            for (int ct = 0; ct < 2; ++ct) {
                int e = wc * 32 + ct * 16 + l15;
                bh[ct] = *(const short8*)&Bs[cur][sub][e * 32 + q8];
            }
            __builtin_amdgcn_s_setprio(1);
#pragma unroll
            for (int rt = 0; rt < 4; ++rt) {
                int r = wr * 64 + rt * 16 + l15;
                short8 ah = *(const short8*)&As[cur][sub][r * 32 + q8];
#pragma unroll
                for (int ct = 0; ct < 2; ++ct)
                    accP[rt][ct] = __builtin_amdgcn_mfma_f32_16x16x32_bf16(ah, bh[ct], accP[rt][ct], 0, 0, 0);
            }
            __builtin_amdgcn_s_setprio(0);
        }

        if ((st & 1) == 1) {
            float wcur = swei[st >> 1];
#pragma unroll
            for (int rt = 0; rt < 4; ++rt)
#pragma unroll
                for (int ct = 0; ct < 2; ++ct)
#pragma unroll
                    for (int reg = 0; reg < 4; ++reg)
                        accT[rt][ct][reg] += wcur * accP[rt][ct][reg];
        }

        if (st + 2 < NT) {
            int tgt = cur ? cur - 1 : 2;        // (cur+2)%3
            stage(st + 2, tgt);
            if (w < 2) asm volatile("s_waitcnt vmcnt(8)" ::: "memory");
            else       asm volatile("s_waitcnt vmcnt(4)" ::: "memory");
        } else if (st + 1 < NT) {
            asm volatile("s_waitcnt vmcnt(0)" ::: "memory");
        }
        cur = (cur == 2) ? 0 : cur + 1;
    }

#pragma unroll
    for (int rt = 0; rt < 4; ++rt)
#pragma unroll
        for (int ct = 0; ct < 2; ++ct) {
#pragma unroll
            for (int reg = 0; reg < 4; ++reg) {
                int row = wr * 64 + rt * 16 + quad * 4 + reg;
                int col = wc * 32 + ct * 16 + l15;
                size_t o = ((size_t)(b * TLEN + n * CS + row)) * EDIM + e0 + col;
                out[o] = accT[rt][ct][reg] + x[o];
            }
        }
}

// ---------------------------------------------------------------------------
extern "C" void kernel_launch(void* const* d_in, const int* in_sizes, int n_in,
                              void* d_out, int out_size, void* d_ws, size_t ws_size,
                              hipStream_t stream) {
    const float* x  = (const float*)d_in[0];   // [2, 8192, 256] fp32
    const float* dp = (const float*)d_in[1];   // [128, 1024] fp32
    float* out = (float*)d_out;

    char* ws = (char*)d_ws;
    short* cn_hi  = (short*)(ws);                       // 8 MB
    short* cn_lo  = (short*)(ws + (8u << 20));          // 8 MB
    short* xkt    = (short*)(ws + (16u << 20));         // 8 MB  [b][chunk][kk][e][k32]
    short* dpk    = (short*)(ws + (24u << 20));         // 256 KB [slot][kk][c][k32]
    float* scores = (float*)(ws + (25u << 20));         // 32 KB

    prep_kernel <<<dim3(264), 256, 0, stream>>>(x, dp, cn_hi, cn_lo, xkt, dpk);
    scores_mfma <<<dim3(NCHUNK * (NCHUNK - 1) / 2, NBATCH), 256, 0, stream>>>(cn_hi, cn_lo, scores);
    out_mfma    <<<dim3(4, NCHUNK, NBATCH), 256, 0, stream>>>(x, dpk, xkt, scores, out);
}

// Round 9
// 199.838 us; speedup vs baseline: 1.0298x; 1.0010x over previous
//
#include <hip/hip_runtime.h>
#include <hip/hip_bf16.h>

// Problem constants (fixed by the reference)
#define CS     128
#define EDIM   256
#define NBATCH 2
#define TLEN   8192
#define NCHUNK 64
#define LEXT   1024
#define KSEL   7

typedef __attribute__((ext_vector_type(8))) short   short8;   // 8 bf16 = 4 VGPR (MFMA A/B frag)
typedef __attribute__((ext_vector_type(4))) float   floatx4;  // MFMA C/D frag

__device__ inline short bf16_of(float f) {
    __hip_bfloat16 h = __float2bfloat16(f);
    return *(short*)&h;
}
__device__ inline float f_of_bf16(short s) {
    __hip_bfloat16 h = *(__hip_bfloat16*)&s;
    return __bfloat162float(h);
}

// async global->LDS, 16B per lane; LDS dest = wave-uniform base + lane*16
__device__ inline void gl_lds16(const void* g, void* l) {
    __builtin_amdgcn_global_load_lds(
        (const __attribute__((address_space(1))) unsigned int*)g,
        (__attribute__((address_space(3))) unsigned int*)l, 16, 0, 0);
}

// raw barrier (no compiler vmcnt(0) drain) — counted vmcnt crosses it
#define RAW_BAR() asm volatile("s_barrier" ::: "memory")

// ---------------------------------------------------------------------------
// Fused prep (r1 proven version): one x read -> cn_hi/cn_lo (row-major) +
// xt_hi ([b][e][T]) ; 8 tail blocks convert dp -> dp_hi ([c][L]).
// ---------------------------------------------------------------------------
__global__ __launch_bounds__(256) void prep_kernel(const float* __restrict__ x,
                                                   const float* __restrict__ dp,
                                                   short* __restrict__ cn_hi,
                                                   short* __restrict__ cn_lo,
                                                   short* __restrict__ xt_hi,
                                                   short* __restrict__ dp_hi) {
    const int bx = blockIdx.x;
    if (bx >= 256) {            // dp conversion: 8 blocks x 256 thr x 16 float4
        int t = (bx - 256) * 256 + threadIdx.x;
#pragma unroll
        for (int u = 0; u < 16; ++u) {
            int idx = (t * 16 + u) * 4;
            float4 v = *(const float4*)(dp + idx);
            *(short4*)(dp_hi + idx) =
                make_short4(bf16_of(v.x), bf16_of(v.y), bf16_of(v.z), bf16_of(v.w));
        }
        return;
    }

    __shared__ float tile[64 * 257];   // [t-row][e], pitch 257
    const int b = bx >> 7, t0 = (bx & 127) * 64;
    const int tid = threadIdx.x;
    const int r = tid >> 2, q = tid & 3;   // row r (0..63), quarter q (64 elems)

    const float* src = x + ((size_t)(b * TLEN + t0 + r)) * EDIM + q * 64;
    float* trow = &tile[r * 257 + q * 64];
    float s = 0.f;
#pragma unroll
    for (int u = 0; u < 16; ++u) {
        float4 v = *(const float4*)(src + u * 4);
        s += v.x * v.x + v.y * v.y + v.z * v.z + v.w * v.w;
        trow[u * 4 + 0] = v.x; trow[u * 4 + 1] = v.y;
        trow[u * 4 + 2] = v.z; trow[u * 4 + 3] = v.w;
    }
    s += __shfl_xor(s, 1);
    s += __shfl_xor(s, 2);
    const float rn = 1.0f / (sqrtf(s) + 1e-6f);

    short* ch = cn_hi + ((size_t)(b * TLEN + t0 + r)) * EDIM + q * 64;
    short* cl = cn_lo + ((size_t)(b * TLEN + t0 + r)) * EDIM + q * 64;
#pragma unroll
    for (int u = 0; u < 16; ++u) {
        short hs[4], ls[4];
#pragma unroll
        for (int k2 = 0; k2 < 4; ++k2) {
            float c = trow[u * 4 + k2] * rn;
            hs[k2] = bf16_of(c);
            ls[k2] = bf16_of(c - f_of_bf16(hs[k2]));
        }
        *(short4*)(ch + u * 4) = make_short4(hs[0], hs[1], hs[2], hs[3]);
        *(short4*)(cl + u * 4) = make_short4(ls[0], ls[1], ls[2], ls[3]);
    }
    __syncthreads();

    const int g16 = tid >> 4, tq = tid & 15;
#pragma unroll
    for (int it = 0; it < 16; ++it) {
        int e = g16 + it * 16;
        short hs2[4];
#pragma unroll
        for (int g = 0; g < 4; ++g)
            hs2[g] = bf16_of(tile[(tq * 4 + g) * 257 + e]);
        *(short4*)(xt_hi + ((size_t)(b * EDIM + e)) * TLEN + t0 + tq * 4)
            = make_short4(hs2[0], hs2[1], hs2[2], hs2[3]);
    }
}

// ---------------------------------------------------------------------------
// Stage B (r1 proven version, verbatim — measured 110.2/110.8/111.6 us,
// MfmaUtil ~40%, conflicts 0; all r2-r6 experiments failed to beat it):
// split-bf16 16x16x32 MFMA cosine scores, XOR bank swizzle, double-buffered
// LDS (64 KB), counted vmcnt(8) across raw barriers, setprio.
// ---------------------------------------------------------------------------
__global__ __launch_bounds__(256) void scores_mfma(const short* __restrict__ cn_hi,
                                                   const short* __restrict__ cn_lo,
                                                   float* __restrict__ scores) {
    __shared__ short tiles[2][4][4096];         // [buf][tile][..] 64 KB exactly
    double* red2   = (double*)&tiles[0][0][0];  // alias (epilogue only)
    float*  redbuf = (float*)&tiles[0][0][8];   // alias, bytes [16, 1040)

    const int p = blockIdx.x, b = blockIdx.y;
    int i = (int)((1.0f + sqrtf(1.0f + 8.0f * (float)p)) * 0.5f);
    while (i * (i - 1) / 2 > p) --i;
    while (i * (i + 1) / 2 <= p) ++i;
    const int j = p - i * (i - 1) / 2;

    const int tid  = threadIdx.x;
    const int w    = tid >> 6, lane = tid & 63;
    const int wr   = w >> 1, wc = w & 1;
    const int quad = lane >> 4, l15 = lane & 15;

    const short* sarr  = (w & 1) ? cn_lo : cn_hi;
    const size_t sbase = ((size_t)b * TLEN + ((w >> 1) ? j : i) * CS) * EDIM;
    const int rr  = lane >> 2;
    const int c16 = (lane & 3) * 8;
    const int csw = c16 ^ (((rr >> 1) & 3) * 8);       // staging swizzle
    const int q8  = (quad ^ ((l15 >> 1) & 3)) * 8;     // frag-read swizzle

    // each wave stages its own tile (w: A_hi / A_lo / B_hi / B_lo), 8x1KB
    auto stage = [&](int ks, int bf) {
        const short* gsrc = sarr + sbase + ks * 32 + csw;
        short* ldst = &tiles[bf][w][0];
#pragma unroll
        for (int t = 0; t < 8; ++t)
            gl_lds16(gsrc + (size_t)(16 * t + rr) * EDIM, ldst + t * 512);
    };

    floatx4 acc[4][4];
#pragma unroll
    for (int rt = 0; rt < 4; ++rt)
#pragma unroll
        for (int ct = 0; ct < 4; ++ct) acc[rt][ct] = (floatx4){0.f, 0.f, 0.f, 0.f};

    stage(0, 0);
    int buf = 0;
    for (int ks = 0; ks < 8; ++ks) {
        if (ks < 7) {
            stage(ks + 1, buf ^ 1);                       // 8 loads in flight
            asm volatile("s_waitcnt vmcnt(8)" ::: "memory");  // old 8 landed
        } else {
            asm volatile("s_waitcnt vmcnt(0)" ::: "memory");
        }
        RAW_BAR();   // all waves' current-buf loads have landed

        short8 bh[4], bl[4];
#pragma unroll
        for (int ct = 0; ct < 4; ++ct) {
            int r = wc * 64 + ct * 16 + l15;
            bh[ct] = *(const short8*)&tiles[buf][2][r * 32 + q8];
            bl[ct] = *(const short8*)&tiles[buf][3][r * 32 + q8];
        }
        __builtin_amdgcn_s_setprio(1);
#pragma unroll
        for (int rt = 0; rt < 4; ++rt) {
            int r = wr * 64 + rt * 16 + l15;
            short8 ah = *(const short8*)&tiles[buf][0][r * 32 + q8];
            short8 al = *(const short8*)&tiles[buf][1][r * 32 + q8];
#pragma unroll
            for (int ct = 0; ct < 4; ++ct) {
                acc[rt][ct] = __builtin_amdgcn_mfma_f32_16x16x32_bf16(ah, bh[ct], acc[rt][ct], 0, 0, 0);
                acc[rt][ct] = __builtin_amdgcn_mfma_f32_16x16x32_bf16(ah, bl[ct], acc[rt][ct], 0, 0, 0);
                acc[rt][ct] = __builtin_amdgcn_mfma_f32_16x16x32_bf16(al, bh[ct], acc[rt][ct], 0, 0, 0);
            }
        }
        __builtin_amdgcn_s_setprio(0);
        RAW_BAR();   // all waves done reading buf before next stage overwrites
        buf ^= 1;
    }

#pragma unroll
    for (int rt = 0; rt < 4; ++rt) {
        float m[4];
#pragma unroll
        for (int reg = 0; reg < 4; ++reg) {
            float mm = acc[rt][0][reg];
#pragma unroll
            for (int ct = 1; ct < 4; ++ct) mm = fmaxf(mm, acc[rt][ct][reg]);
            m[reg] = mm;
        }
#pragma unroll
        for (int off = 1; off < 16; off <<= 1)
#pragma unroll
            for (int reg = 0; reg < 4; ++reg) m[reg] = fmaxf(m[reg], __shfl_xor(m[reg], off));
        if (l15 == 0) {
#pragma unroll
            for (int reg = 0; reg < 4; ++reg)
                redbuf[wc * 128 + wr * 64 + rt * 16 + quad * 4 + reg] = m[reg];
        }
    }
    __syncthreads();

    double part = 0.0;
    if (tid < 128) part = (double)fmaxf(redbuf[tid], redbuf[128 + tid]);
#pragma unroll
    for (int off = 1; off < 64; off <<= 1) part += __shfl_xor(part, off);
    if (lane == 0 && w < 2) red2[w] = part;
    __syncthreads();
    if (tid == 0) scores[(b * NCHUNK + i) * NCHUNK + j] = (float)(red2[0] + red2[1]);
}

// ---------------------------------------------------------------------------
// Stage D v7 (measured best, rest = 84.4 us in round 3): out = dp @ ext +
// chunk, K=64 steps (2 k32 sub-slices each), 3 LDS buffers, prefetch depth 2,
// ONE raw barrier per step, counted per-wave vmcnt. dph = [c][L], xth =
// [b][e][T] (r1 prep outputs). Verbatim.
// ---------------------------------------------------------------------------
__global__ __launch_bounds__(256) void out_mfma(const float* __restrict__ x,
                                                const short* __restrict__ dph,
                                                const short* __restrict__ xth,
                                                const float* __restrict__ scores,
                                                float* __restrict__ out) {
    __shared__ short As[3][2][128 * 32];   // [buf][sub][c][k]  48 KB
    __shared__ short Bs[3][2][64 * 32];    // [buf][sub][e][k]  24 KB
    __shared__ int   slist[8], sslot[8], snum;
    __shared__ float swei[8];

    const int eq = blockIdx.x, n = blockIdx.y, b = blockIdx.z;
    const int e0 = eq * 64;
    const int tid  = threadIdx.x;
    const int w    = tid >> 6, lane = tid & 63;
    const int wr   = w >> 1, wc = w & 1;
    const int quad = lane >> 4, l15 = lane & 15;
    const int rr   = lane >> 2;
    const int c16  = (lane & 3) * 8;
    const int csw  = c16 ^ (((rr >> 1) & 3) * 8);
    const int q8   = (quad ^ ((l15 >> 1) & 3)) * 8;

    // ---- inlined top-7 (wave 0): candidates j in [0, n) ----
    if (w == 0) {
        const float* srow = scores + (b * NCHUNK + n) * NCHUNK;
        const int nsel = n < KSEL ? n : KSEL;
        float v = (lane < n) ? srow[lane] : -3.0e38f;
        float vals[KSEL];
        int   idxs[KSEL];
        for (int s2 = 0; s2 < nsel; ++s2) {
            float bv = v; int bi = lane;
#pragma unroll
            for (int off = 1; off < 64; off <<= 1) {
                float ov = __shfl_xor(bv, off);
                int   oi = __shfl_xor(bi, off);
                if (ov > bv || (ov == bv && oi < bi)) { bv = ov; bi = oi; }
            }
            vals[s2] = bv; idxs[s2] = bi;
            if (lane == bi) v = -3.0e38f;
        }
        if (lane == 0) {
            float vmin = (nsel > 0) ? vals[nsel - 1] : 0.0f;
            float inv  = 1.0f / (vmin + 1e-6f);
            int shift  = KSEL - nsel;
            int c = 0;
            for (int s2 = 0; s2 < 8; ++s2) {
                int jj; float ww;
                if (s2 < KSEL) {
                    int tt = s2 - shift;
                    if (tt >= 0) { jj = idxs[tt]; ww = vals[tt] * inv; }
                    else         { jj = -1;       ww = 0.0f; }
                } else { jj = n; ww = 1.0f; }
                if (jj >= 0) { slist[c] = jj; sslot[c] = s2; swei[c] = ww; ++c; }
            }
            snum = c;
        }
    }
    __syncthreads();
    const int NT = snum * 2;   // K=64 steps (2 k32 sub-slices per step)

    // stage step st into buffer b3: waves 0-1 stage As (8 loads), 2-3 Bs (4)
    auto stage = [&](int st, int b3) {
        int sv = st >> 1, kh = st & 1;
        if (w < 2) {
#pragma unroll
            for (int sub = 0; sub < 2; ++sub) {
                const short* gsrc = dph + (size_t)(sslot[sv] * 128 + (kh * 2 + sub) * 32) + csw;
#pragma unroll
                for (int t = 0; t < 4; ++t)
                    gl_lds16(gsrc + (size_t)(w * 64 + t * 16 + rr) * LEXT,
                             &As[b3][sub][(w * 64 + t * 16) * 32]);
            }
        } else {
#pragma unroll
            for (int sub = 0; sub < 2; ++sub) {
                const short* gsrc = xth + ((size_t)(b * EDIM + e0)) * TLEN
                                    + (size_t)(slist[sv] * CS + (kh * 2 + sub) * 32) + csw;
#pragma unroll
                for (int t = 0; t < 2; ++t)
                    gl_lds16(gsrc + (size_t)((w - 2) * 32 + t * 16 + rr) * TLEN,
                             &Bs[b3][sub][((w - 2) * 32 + t * 16) * 32]);
            }
        }
    };

    floatx4 accT[4][2], accP[4][2];
#pragma unroll
    for (int rt = 0; rt < 4; ++rt)
#pragma unroll
        for (int ct = 0; ct < 2; ++ct) accT[rt][ct] = (floatx4){0.f, 0.f, 0.f, 0.f};

    stage(0, 0);
    if (NT > 1) stage(1, 1);
    // ensure stage 0 landed (allow stage 1's loads to remain in flight)
    if (w < 2) asm volatile("s_waitcnt vmcnt(8)" ::: "memory");
    else       asm volatile("s_waitcnt vmcnt(4)" ::: "memory");

    int cur = 0;
    for (int st = 0; st < NT; ++st) {
        RAW_BAR();   // all waves: buf 'cur' landed, and compute(st-1) finished

        if ((st & 1) == 0) {
#pragma unroll
            for (int rt = 0; rt < 4; ++rt)
#pragma unroll
                for (int ct = 0; ct < 2; ++ct) accP[rt][ct] = (floatx4){0.f, 0.f, 0.f, 0.f};
        }

#pragma unroll
        for (int sub = 0; sub < 2; ++sub) {
            short8 bh[2];
#pragma unroll
            for (int ct = 0; ct < 2; ++ct) {
                int e = wc * 32 + ct * 16 + l15;
                bh[ct] = *(const short8*)&Bs[cur][sub][e * 32 + q8];
            }
            __builtin_amdgcn_s_setprio(1);
#pragma unroll
            for (int rt = 0; rt < 4; ++rt) {
                int r = wr * 64 + rt * 16 + l15;
                short8 ah = *(const short8*)&As[cur][sub][r * 32 + q8];
#pragma unroll
                for (int ct = 0; ct < 2; ++ct)
                    accP[rt][ct] = __builtin_amdgcn_mfma_f32_16x16x32_bf16(ah, bh[ct], accP[rt][ct], 0, 0, 0);
            }
            __builtin_amdgcn_s_setprio(0);
        }

        if ((st & 1) == 1) {
            float wcur = swei[st >> 1];
#pragma unroll
            for (int rt = 0; rt < 4; ++rt)
#pragma unroll
                for (int ct = 0; ct < 2; ++ct)
#pragma unroll
                    for (int reg = 0; reg < 4; ++reg)
                        accT[rt][ct][reg] += wcur * accP[rt][ct][reg];
        }

        if (st + 2 < NT) {
            int tgt = cur ? cur - 1 : 2;        // (cur+2)%3
            stage(st + 2, tgt);
            if (w < 2) asm volatile("s_waitcnt vmcnt(8)" ::: "memory");
            else       asm volatile("s_waitcnt vmcnt(4)" ::: "memory");
        } else if (st + 1 < NT) {
            asm volatile("s_waitcnt vmcnt(0)" ::: "memory");
        }
        cur = (cur == 2) ? 0 : cur + 1;
    }

#pragma unroll
    for (int rt = 0; rt < 4; ++rt)
#pragma unroll
        for (int ct = 0; ct < 2; ++ct) {
#pragma unroll
            for (int reg = 0; reg < 4; ++reg) {
                int row = wr * 64 + rt * 16 + quad * 4 + reg;
                int col = wc * 32 + ct * 16 + l15;
                size_t o = ((size_t)(b * TLEN + n * CS + row)) * EDIM + e0 + col;
                out[o] = accT[rt][ct][reg] + x[o];
            }
        }
}

// ---------------------------------------------------------------------------
extern "C" void kernel_launch(void* const* d_in, const int* in_sizes, int n_in,
                              void* d_out, int out_size, void* d_ws, size_t ws_size,
                              hipStream_t stream) {
    const float* x  = (const float*)d_in[0];   // [2, 8192, 256] fp32
    const float* dp = (const float*)d_in[1];   // [128, 1024] fp32
    float* out = (float*)d_out;

    char* ws = (char*)d_ws;
    short* cn_hi  = (short*)(ws);                       // 8 MB
    short* cn_lo  = (short*)(ws + (8u << 20));          // 8 MB
    short* xt_hi  = (short*)(ws + (16u << 20));         // 8 MB  [b][e][T]
    short* dp_hi  = (short*)(ws + (24u << 20));         // 256 KB [c][L]
    float* scores = (float*)(ws + (25u << 20));         // 32 KB

    prep_kernel <<<dim3(264), 256, 0, stream>>>(x, dp, cn_hi, cn_lo, xt_hi, dp_hi);
    scores_mfma <<<dim3(NCHUNK * (NCHUNK - 1) / 2, NBATCH), 256, 0, stream>>>(cn_hi, cn_lo, scores);
    out_mfma    <<<dim3(4, NCHUNK, NBATCH), 256, 0, stream>>>(x, dp_hi, xt_hi, scores, out);
}

// Round 10
// 199.316 us; speedup vs baseline: 1.0325x; 1.0026x over previous
//
#include <hip/hip_runtime.h>
#include <hip/hip_bf16.h>

// Problem constants (fixed by the reference)
#define CS     128
#define EDIM   256
#define NBATCH 2
#define TLEN   8192
#define NCHUNK 64
#define LEXT   1024
#define KSEL   7

typedef __attribute__((ext_vector_type(8))) short   short8;   // 8 bf16 = 4 VGPR (MFMA A/B frag)
typedef __attribute__((ext_vector_type(4))) float   floatx4;  // MFMA C/D frag

__device__ inline short bf16_of(float f) {
    __hip_bfloat16 h = __float2bfloat16(f);
    return *(short*)&h;
}
__device__ inline float f_of_bf16(short s) {
    __hip_bfloat16 h = *(__hip_bfloat16*)&s;
    return __bfloat162float(h);
}

// async global->LDS, 16B per lane; LDS dest = wave-uniform base + lane*16
__device__ inline void gl_lds16(const void* g, void* l) {
    __builtin_amdgcn_global_load_lds(
        (const __attribute__((address_space(1))) unsigned int*)g,
        (__attribute__((address_space(3))) unsigned int*)l, 16, 0, 0);
}

// raw barrier (no compiler vmcnt(0) drain) — counted vmcnt crosses it
#define RAW_BAR() asm volatile("s_barrier" ::: "memory")

// ---------------------------------------------------------------------------
// Fused prep v2: identical layouts to the r1 proven version (cn row-major,
// xt_hi [b][e][T], dp_hi [c][L]) with every store widened 8B -> 16B
// (short4 -> short8). G13: hipcc doesn't auto-widen bf16 stores; 16B/lane
// is the coalescing sweet spot. Same bytes, half the store instructions.
// ---------------------------------------------------------------------------
__global__ __launch_bounds__(256) void prep_kernel(const float* __restrict__ x,
                                                   const float* __restrict__ dp,
                                                   short* __restrict__ cn_hi,
                                                   short* __restrict__ cn_lo,
                                                   short* __restrict__ xt_hi,
                                                   short* __restrict__ dp_hi) {
    const int bx = blockIdx.x;
    if (bx >= 256) {            // dp conversion: 8 blocks x 256 thr, short8 stores
        int t = (bx - 256) * 256 + threadIdx.x;
#pragma unroll
        for (int u = 0; u < 8; ++u) {
            int idx = (t * 16 + u * 2) * 4;
            float4 v0 = *(const float4*)(dp + idx);
            float4 v1 = *(const float4*)(dp + idx + 4);
            short8 sv;
            sv[0] = bf16_of(v0.x); sv[1] = bf16_of(v0.y);
            sv[2] = bf16_of(v0.z); sv[3] = bf16_of(v0.w);
            sv[4] = bf16_of(v1.x); sv[5] = bf16_of(v1.y);
            sv[6] = bf16_of(v1.z); sv[7] = bf16_of(v1.w);
            *(short8*)(dp_hi + idx) = sv;
        }
        return;
    }

    __shared__ float tile[64 * 257];   // [t-row][e], pitch 257
    const int b = bx >> 7, t0 = (bx & 127) * 64;
    const int tid = threadIdx.x;
    const int r = tid >> 2, q = tid & 3;   // row r (0..63), quarter q (64 elems)

    const float* src = x + ((size_t)(b * TLEN + t0 + r)) * EDIM + q * 64;
    float* trow = &tile[r * 257 + q * 64];
    float s = 0.f;
#pragma unroll
    for (int u = 0; u < 16; ++u) {
        float4 v = *(const float4*)(src + u * 4);
        s += v.x * v.x + v.y * v.y + v.z * v.z + v.w * v.w;
        trow[u * 4 + 0] = v.x; trow[u * 4 + 1] = v.y;
        trow[u * 4 + 2] = v.z; trow[u * 4 + 3] = v.w;
    }
    s += __shfl_xor(s, 1);
    s += __shfl_xor(s, 2);
    const float rn = 1.0f / (sqrtf(s) + 1e-6f);

    short* ch = cn_hi + ((size_t)(b * TLEN + t0 + r)) * EDIM + q * 64;
    short* cl = cn_lo + ((size_t)(b * TLEN + t0 + r)) * EDIM + q * 64;
#pragma unroll
    for (int u = 0; u < 8; ++u) {
        short8 hv, lv;
#pragma unroll
        for (int k2 = 0; k2 < 8; ++k2) {
            float c = trow[u * 8 + k2] * rn;
            short hh = bf16_of(c);
            hv[k2] = hh;
            lv[k2] = bf16_of(c - f_of_bf16(hh));
        }
        *(short8*)(ch + u * 8) = hv;
        *(short8*)(cl + u * 8) = lv;
    }
    __syncthreads();

    // xt_hi write ([b][e][T] unchanged): thread (g32 = tid>>3, tq8 = tid&7)
    // covers e = g32 + it*32 (it 0..7), t = t0 + tq8*8 .. +7 -> short8 store.
    const int g32 = tid >> 3, tq8 = tid & 7;
#pragma unroll
    for (int it = 0; it < 8; ++it) {
        int e = g32 + it * 32;
        short8 hv;
#pragma unroll
        for (int g = 0; g < 8; ++g)
            hv[g] = bf16_of(tile[(tq8 * 8 + g) * 257 + e]);
        *(short8*)(xt_hi + ((size_t)(b * EDIM + e)) * TLEN + t0 + tq8 * 8) = hv;
    }
}

// ---------------------------------------------------------------------------
// Stage B (r1 proven version, verbatim — measured 110.2/110.8/111.2/111.6 us,
// MfmaUtil ~40%, conflicts 0; all r2-r6 experiments failed to beat it):
// split-bf16 16x16x32 MFMA cosine scores, XOR bank swizzle, double-buffered
// LDS (64 KB), counted vmcnt(8) across raw barriers, setprio.
// ---------------------------------------------------------------------------
__global__ __launch_bounds__(256) void scores_mfma(const short* __restrict__ cn_hi,
                                                   const short* __restrict__ cn_lo,
                                                   float* __restrict__ scores) {
    __shared__ short tiles[2][4][4096];         // [buf][tile][..] 64 KB exactly
    double* red2   = (double*)&tiles[0][0][0];  // alias (epilogue only)
    float*  redbuf = (float*)&tiles[0][0][8];   // alias, bytes [16, 1040)

    const int p = blockIdx.x, b = blockIdx.y;
    int i = (int)((1.0f + sqrtf(1.0f + 8.0f * (float)p)) * 0.5f);
    while (i * (i - 1) / 2 > p) --i;
    while (i * (i + 1) / 2 <= p) ++i;
    const int j = p - i * (i - 1) / 2;

    const int tid  = threadIdx.x;
    const int w    = tid >> 6, lane = tid & 63;
    const int wr   = w >> 1, wc = w & 1;
    const int quad = lane >> 4, l15 = lane & 15;

    const short* sarr  = (w & 1) ? cn_lo : cn_hi;
    const size_t sbase = ((size_t)b * TLEN + ((w >> 1) ? j : i) * CS) * EDIM;
    const int rr  = lane >> 2;
    const int c16 = (lane & 3) * 8;
    const int csw = c16 ^ (((rr >> 1) & 3) * 8);       // staging swizzle
    const int q8  = (quad ^ ((l15 >> 1) & 3)) * 8;     // frag-read swizzle

    // each wave stages its own tile (w: A_hi / A_lo / B_hi / B_lo), 8x1KB
    auto stage = [&](int ks, int bf) {
        const short* gsrc = sarr + sbase + ks * 32 + csw;
        short* ldst = &tiles[bf][w][0];
#pragma unroll
        for (int t = 0; t < 8; ++t)
            gl_lds16(gsrc + (size_t)(16 * t + rr) * EDIM, ldst + t * 512);
    };

    floatx4 acc[4][4];
#pragma unroll
    for (int rt = 0; rt < 4; ++rt)
#pragma unroll
        for (int ct = 0; ct < 4; ++ct) acc[rt][ct] = (floatx4){0.f, 0.f, 0.f, 0.f};

    stage(0, 0);
    int buf = 0;
    for (int ks = 0; ks < 8; ++ks) {
        if (ks < 7) {
            stage(ks + 1, buf ^ 1);                       // 8 loads in flight
            asm volatile("s_waitcnt vmcnt(8)" ::: "memory");  // old 8 landed
        } else {
            asm volatile("s_waitcnt vmcnt(0)" ::: "memory");
        }
        RAW_BAR();   // all waves' current-buf loads have landed

        short8 bh[4], bl[4];
#pragma unroll
        for (int ct = 0; ct < 4; ++ct) {
            int r = wc * 64 + ct * 16 + l15;
            bh[ct] = *(const short8*)&tiles[buf][2][r * 32 + q8];
            bl[ct] = *(const short8*)&tiles[buf][3][r * 32 + q8];
        }
        __builtin_amdgcn_s_setprio(1);
#pragma unroll
        for (int rt = 0; rt < 4; ++rt) {
            int r = wr * 64 + rt * 16 + l15;
            short8 ah = *(const short8*)&tiles[buf][0][r * 32 + q8];
            short8 al = *(const short8*)&tiles[buf][1][r * 32 + q8];
#pragma unroll
            for (int ct = 0; ct < 4; ++ct) {
                acc[rt][ct] = __builtin_amdgcn_mfma_f32_16x16x32_bf16(ah, bh[ct], acc[rt][ct], 0, 0, 0);
                acc[rt][ct] = __builtin_amdgcn_mfma_f32_16x16x32_bf16(ah, bl[ct], acc[rt][ct], 0, 0, 0);
                acc[rt][ct] = __builtin_amdgcn_mfma_f32_16x16x32_bf16(al, bh[ct], acc[rt][ct], 0, 0, 0);
            }
        }
        __builtin_amdgcn_s_setprio(0);
        RAW_BAR();   // all waves done reading buf before next stage overwrites
        buf ^= 1;
    }

#pragma unroll
    for (int rt = 0; rt < 4; ++rt) {
        float m[4];
#pragma unroll
        for (int reg = 0; reg < 4; ++reg) {
            float mm = acc[rt][0][reg];
#pragma unroll
            for (int ct = 1; ct < 4; ++ct) mm = fmaxf(mm, acc[rt][ct][reg]);
            m[reg] = mm;
        }
#pragma unroll
        for (int off = 1; off < 16; off <<= 1)
#pragma unroll
            for (int reg = 0; reg < 4; ++reg) m[reg] = fmaxf(m[reg], __shfl_xor(m[reg], off));
        if (l15 == 0) {
#pragma unroll
            for (int reg = 0; reg < 4; ++reg)
                redbuf[wc * 128 + wr * 64 + rt * 16 + quad * 4 + reg] = m[reg];
        }
    }
    __syncthreads();

    double part = 0.0;
    if (tid < 128) part = (double)fmaxf(redbuf[tid], redbuf[128 + tid]);
#pragma unroll
    for (int off = 1; off < 64; off <<= 1) part += __shfl_xor(part, off);
    if (lane == 0 && w < 2) red2[w] = part;
    __syncthreads();
    if (tid == 0) scores[(b * NCHUNK + i) * NCHUNK + j] = (float)(red2[0] + red2[1]);
}

// ---------------------------------------------------------------------------
// Stage D v7 (measured best): out = dp @ ext + chunk, K=64 steps (2 k32
// sub-slices each), 3 LDS buffers, prefetch depth 2, ONE raw barrier per
// step, counted per-wave vmcnt. dph = [c][L], xth = [b][e][T]. Verbatim.
// ---------------------------------------------------------------------------
__global__ __launch_bounds__(256) void out_mfma(const float* __restrict__ x,
                                                const short* __restrict__ dph,
                                                const short* __restrict__ xth,
                                                const float* __restrict__ scores,
                                                float* __restrict__ out) {
    __shared__ short As[3][2][128 * 32];   // [buf][sub][c][k]  48 KB
    __shared__ short Bs[3][2][64 * 32];    // [buf][sub][e][k]  24 KB
    __shared__ int   slist[8], sslot[8], snum;
    __shared__ float swei[8];

    const int eq = blockIdx.x, n = blockIdx.y, b = blockIdx.z;
    const int e0 = eq * 64;
    const int tid  = threadIdx.x;
    const int w    = tid >> 6, lane = tid & 63;
    const int wr   = w >> 1, wc = w & 1;
    const int quad = lane >> 4, l15 = lane & 15;
    const int rr   = lane >> 2;
    const int c16  = (lane & 3) * 8;
    const int csw  = c16 ^ (((rr >> 1) & 3) * 8);
    const int q8   = (quad ^ ((l15 >> 1) & 3)) * 8;

    // ---- inlined top-7 (wave 0): candidates j in [0, n) ----
    if (w == 0) {
        const float* srow = scores + (b * NCHUNK + n) * NCHUNK;
        const int nsel = n < KSEL ? n : KSEL;
        float v = (lane < n) ? srow[lane] : -3.0e38f;
        float vals[KSEL];
        int   idxs[KSEL];
        for (int s2 = 0; s2 < nsel; ++s2) {
            float bv = v; int bi = lane;
#pragma unroll
            for (int off = 1; off < 64; off <<= 1) {
                float ov = __shfl_xor(bv, off);
                int   oi = __shfl_xor(bi, off);
                if (ov > bv || (ov == bv && oi < bi)) { bv = ov; bi = oi; }
            }
            vals[s2] = bv; idxs[s2] = bi;
            if (lane == bi) v = -3.0e38f;
        }
        if (lane == 0) {
            float vmin = (nsel > 0) ? vals[nsel - 1] : 0.0f;
            float inv  = 1.0f / (vmin + 1e-6f);
            int shift  = KSEL - nsel;
            int c = 0;
            for (int s2 = 0; s2 < 8; ++s2) {
                int jj; float ww;
                if (s2 < KSEL) {
                    int tt = s2 - shift;
                    if (tt >= 0) { jj = idxs[tt]; ww = vals[tt] * inv; }
                    else         { jj = -1;       ww = 0.0f; }
                } else { jj = n; ww = 1.0f; }
                if (jj >= 0) { slist[c] = jj; sslot[c] = s2; swei[c] = ww; ++c; }
            }
            snum = c;
        }
    }
    __syncthreads();
    const int NT = snum * 2;   // K=64 steps (2 k32 sub-slices per step)

    // stage step st into buffer b3: waves 0-1 stage As (8 loads), 2-3 Bs (4)
    auto stage = [&](int st, int b3) {
        int sv = st >> 1, kh = st & 1;
        if (w < 2) {
#pragma unroll
            for (int sub = 0; sub < 2; ++sub) {
                const short* gsrc = dph + (size_t)(sslot[sv] * 128 + (kh * 2 + sub) * 32) + csw;
#pragma unroll
                for (int t = 0; t < 4; ++t)
                    gl_lds16(gsrc + (size_t)(w * 64 + t * 16 + rr) * LEXT,
                             &As[b3][sub][(w * 64 + t * 16) * 32]);
            }
        } else {
#pragma unroll
            for (int sub = 0; sub < 2; ++sub) {
                const short* gsrc = xth + ((size_t)(b * EDIM + e0)) * TLEN
                                    + (size_t)(slist[sv] * CS + (kh * 2 + sub) * 32) + csw;
#pragma unroll
                for (int t = 0; t < 2; ++t)
                    gl_lds16(gsrc + (size_t)((w - 2) * 32 + t * 16 + rr) * TLEN,
                             &Bs[b3][sub][((w - 2) * 32 + t * 16) * 32]);
            }
        }
    };

    floatx4 accT[4][2], accP[4][2];
#pragma unroll
    for (int rt = 0; rt < 4; ++rt)
#pragma unroll
        for (int ct = 0; ct < 2; ++ct) accT[rt][ct] = (floatx4){0.f, 0.f, 0.f, 0.f};

    stage(0, 0);
    if (NT > 1) stage(1, 1);
    // ensure stage 0 landed (allow stage 1's loads to remain in flight)
    if (w < 2) asm volatile("s_waitcnt vmcnt(8)" ::: "memory");
    else       asm volatile("s_waitcnt vmcnt(4)" ::: "memory");

    int cur = 0;
    for (int st = 0; st < NT; ++st) {
        RAW_BAR();   // all waves: buf 'cur' landed, and compute(st-1) finished

        if ((st & 1) == 0) {
#pragma unroll
            for (int rt = 0; rt < 4; ++rt)
#pragma unroll
                for (int ct = 0; ct < 2; ++ct) accP[rt][ct] = (floatx4){0.f, 0.f, 0.f, 0.f};
        }

#pragma unroll
        for (int sub = 0; sub < 2; ++sub) {
            short8 bh[2];
#pragma unroll
            for (int ct = 0; ct < 2; ++ct) {
                int e = wc * 32 + ct * 16 + l15;
                bh[ct] = *(const short8*)&Bs[cur][sub][e * 32 + q8];
            }
            __builtin_amdgcn_s_setprio(1);
#pragma unroll
            for (int rt = 0; rt < 4; ++rt) {
                int r = wr * 64 + rt * 16 + l15;
                short8 ah = *(const short8*)&As[cur][sub][r * 32 + q8];
#pragma unroll
                for (int ct = 0; ct < 2; ++ct)
                    accP[rt][ct] = __builtin_amdgcn_mfma_f32_16x16x32_bf16(ah, bh[ct], accP[rt][ct], 0, 0, 0);
            }
            __builtin_amdgcn_s_setprio(0);
        }

        if ((st & 1) == 1) {
            float wcur = swei[st >> 1];
#pragma unroll
            for (int rt = 0; rt < 4; ++rt)
#pragma unroll
                for (int ct = 0; ct < 2; ++ct)
#pragma unroll
                    for (int reg = 0; reg < 4; ++reg)
                        accT[rt][ct][reg] += wcur * accP[rt][ct][reg];
        }

        if (st + 2 < NT) {
            int tgt = cur ? cur - 1 : 2;        // (cur+2)%3
            stage(st + 2, tgt);
            if (w < 2) asm volatile("s_waitcnt vmcnt(8)" ::: "memory");
            else       asm volatile("s_waitcnt vmcnt(4)" ::: "memory");
        } else if (st + 1 < NT) {
            asm volatile("s_waitcnt vmcnt(0)" ::: "memory");
        }
        cur = (cur == 2) ? 0 : cur + 1;
    }

#pragma unroll
    for (int rt = 0; rt < 4; ++rt)
#pragma unroll
        for (int ct = 0; ct < 2; ++ct) {
#pragma unroll
            for (int reg = 0; reg < 4; ++reg) {
                int row = wr * 64 + rt * 16 + quad * 4 + reg;
                int col = wc * 32 + ct * 16 + l15;
                size_t o = ((size_t)(b * TLEN + n * CS + row)) * EDIM + e0 + col;
                out[o] = accT[rt][ct][reg] + x[o];
            }
        }
}

// ---------------------------------------------------------------------------
extern "C" void kernel_launch(void* const* d_in, const int* in_sizes, int n_in,
                              void* d_out, int out_size, void* d_ws, size_t ws_size,
                              hipStream_t stream) {
    const float* x  = (const float*)d_in[0];   // [2, 8192, 256] fp32
    const float* dp = (const float*)d_in[1];   // [128, 1024] fp32
    float* out = (float*)d_out;

    char* ws = (char*)d_ws;
    short* cn_hi  = (short*)(ws);                       // 8 MB
    short* cn_lo  = (short*)(ws + (8u << 20));          // 8 MB
    short* xt_hi  = (short*)(ws + (16u << 20));         // 8 MB  [b][e][T]
    short* dp_hi  = (short*)(ws + (24u << 20));         // 256 KB [c][L]
    float* scores = (float*)(ws + (25u << 20));         // 32 KB

    prep_kernel <<<dim3(264), 256, 0, stream>>>(x, dp, cn_hi, cn_lo, xt_hi, dp_hi);
    scores_mfma <<<dim3(NCHUNK * (NCHUNK - 1) / 2, NBATCH), 256, 0, stream>>>(cn_hi, cn_lo, scores);
    out_mfma    <<<dim3(4, NCHUNK, NBATCH), 256, 0, stream>>>(x, dp_hi, xt_hi, scores, out);
}